// Round 1
// baseline (29114.111 us; speedup 1.0000x reference)
//
#include <hip/hip_runtime.h>
#include <cstddef>

#define BB 32
#define TT 2048
#define DD 512
#define LL 512
#define NBLK 32
#define HSZ ((size_t)BB * TT * LL)
#define LDSROW 520   // bf16 elems per staged-h row (512 + 8 pad)
#define PKTS 8192    // u64 packets per phase (32 * 512 / 2)

typedef __attribute__((ext_vector_type(8))) short short8;
typedef __attribute__((ext_vector_type(4))) float floatx4;

__device__ __forceinline__ unsigned short f2bf(float f) {
  __bf16 b = (__bf16)f;
  return __builtin_bit_cast(unsigned short, b);
}

__device__ __forceinline__ short8 pack2(const float4& a, const float4& b) {
  short8 r;
  r[0] = (short)f2bf(a.x); r[1] = (short)f2bf(a.y);
  r[2] = (short)f2bf(a.z); r[3] = (short)f2bf(a.w);
  r[4] = (short)f2bf(b.x); r[5] = (short)f2bf(b.y);
  r[6] = (short)f2bf(b.z); r[7] = (short)f2bf(b.w);
  return r;
}

__device__ __forceinline__ float sigm(float v) {
  return 1.0f / (1.0f + __expf(-v));
}
__device__ __forceinline__ float tanh_f(float v) {
  return 1.0f - 2.0f / (__expf(2.0f * v) + 1.0f);
}

// 32 persistent blocks; block j owns col-slice `slice` (XCD-paired swizzle).
// Cross-block h-exchange is SINGLE-HOP: producers store u64 packets
// (tag<<32 | bf16 pair) with cache-bypass agent atomics; consumers poll-load
// the packets directly (no flags, no acquire fence, no L2 invalidate).
// 2-phase ping-pong is WAR-safe transitively: reaching step t+2's epilogue
// requires staging h(t+1), which requires tag t+1 from ALL blocks, which is
// only stored after each block staged h(t). Stale tags (poison / prior run)
// can't match the expected tag before the slot is freshly rewritten.
__global__ __launch_bounds__(1024, 4) void lstm_persistent(
    const float* __restrict__ x, const float* __restrict__ h0p,
    const float* __restrict__ c0p, const float* __restrict__ w_w,
    const float* __restrict__ w_b, const float* __restrict__ m_w,
    const float* __restrict__ m_b, float* __restrict__ out,
    unsigned long long* __restrict__ hbuf64) {
  const int j = blockIdx.x;
  const int slice = ((j & 7) << 2) | (j >> 3);  // same-XCD blocks -> adjacent slices
  const int tid = threadIdx.x;
  const int wave = tid >> 6;
  const int lane = tid & 63;
  const int s = wave & 3;    // 0=i, 1=f, 2=o, 3=mem strip
  const int kg = wave >> 2;  // 0,1 = x half; 2,3 = h half
  const int q = lane >> 4;
  const int ln = lane & 15;

  __shared__ __align__(16) float partials[16][16][36];
  __shared__ __align__(16) unsigned short hstage[32 * LDSROW];

  // ---- preload A fragments: W^T slice (k rows 0..1023 = [x|h]) ----
  short8 afrag[8];
  {
    const float* Wsrc;
    int wstride, col;
    if (s < 3) { Wsrc = w_w; wstride = 3 * LL; col = s * LL + slice * 16 + ln; }
    else       { Wsrc = m_w; wstride = LL;     col = slice * 16 + ln; }
#pragma unroll
    for (int kt = 0; kt < 8; ++kt) {
      const int kb = kg * 256 + kt * 32 + q * 8;
      short8 f;
#pragma unroll
      for (int jj = 0; jj < 8; ++jj)
        f[jj] = (short)f2bf(Wsrc[(size_t)(kb + jj) * wstride + col]);
      afrag[kt] = f;
    }
  }

  // ---- epilogue thread state: tid<256 -> (batch eb, l-pair elp) ----
  const int eb = tid >> 3;
  const int elp = tid & 7;
  const int ecol = slice * 16 + elp * 2;
  float cc0 = 0.f, cc1 = 0.f;
  float bi0 = 0, bi1 = 0, bfg0 = 0, bfg1 = 0, bo0 = 0, bo1 = 0, bm0 = 0, bm1 = 0;
  if (tid < 256) {
    cc0 = c0p[eb * LL + ecol];
    cc1 = c0p[eb * LL + ecol + 1];
    bi0 = w_b[ecol];            bi1 = w_b[ecol + 1];
    bfg0 = w_b[LL + ecol];      bfg1 = w_b[LL + ecol + 1];
    bo0 = w_b[2 * LL + ecol];   bo1 = w_b[2 * LL + ecol + 1];
    bm0 = m_b[ecol];            bm1 = m_b[ecol + 1];
  }

#pragma unroll 1
  for (int t = 1; t <= TT; ++t) {
    floatx4 acc0 = {0.f, 0.f, 0.f, 0.f};
    floatx4 acc1 = {0.f, 0.f, 0.f, 0.f};

    if (kg < 2) {
      // ---- x contribution: independent of the recurrence ----
      const size_t row0 = ((size_t)ln * TT + (t - 1)) * DD;
      const size_t row1 = ((size_t)(16 + ln) * TT + (t - 1)) * DD;
      const int kb0 = kg * 256 + q * 8;
#pragma unroll
      for (int kt = 0; kt < 8; ++kt) {
        const int k = kb0 + kt * 32;
        float4 a0 = *(const float4*)(x + row0 + k);
        float4 a1 = *(const float4*)(x + row0 + k + 4);
        float4 c0v = *(const float4*)(x + row1 + k);
        float4 c1v = *(const float4*)(x + row1 + k + 4);
        short8 bA = pack2(a0, a1);
        short8 bB = pack2(c0v, c1v);
        acc0 = __builtin_amdgcn_mfma_f32_16x16x32_bf16(afrag[kt], bA, acc0, 0, 0, 0);
        acc1 = __builtin_amdgcn_mfma_f32_16x16x32_bf16(afrag[kt], bB, acc1, 0, 0, 0);
      }
      const int sg = s * 4 + kg;
#pragma unroll
      for (int r = 0; r < 4; ++r) {
        partials[sg][q * 4 + r][ln] = acc0[r];
        partials[sg][q * 4 + r][16 + ln] = acc1[r];
      }
    } else {
      // ---- stage h(t-1) into LDS: 512 threads x 64 B, poll tags in-data ----
      const int idx = tid - 512;
      const int b = idx & 31;
      const int g = idx >> 5;
      unsigned short* dst = &hstage[b * LDSROW + g * 32];
      if (t == 1) {
        const float* src = h0p + b * LL + g * 32;
#pragma unroll
        for (int i = 0; i < 4; ++i) {
          float4 a0 = *(const float4*)(src + i * 8);
          float4 a1 = *(const float4*)(src + i * 8 + 4);
          *(short8*)(dst + i * 8) = pack2(a0, a1);
        }
      } else {
        const unsigned long long* src =
            hbuf64 + (size_t)((t - 1) & 1) * PKTS + (size_t)b * 256 + g * 16;
        const unsigned int want = (unsigned int)(t - 1);
        unsigned int pay[16];
        for (;;) {
          unsigned int bad = 0;
#pragma unroll
          for (int p = 0; p < 16; ++p) {
            unsigned long long v = __hip_atomic_load(
                src + p, __ATOMIC_RELAXED, __HIP_MEMORY_SCOPE_AGENT);
            pay[p] = (unsigned int)v;
            bad |= ((unsigned int)(v >> 32)) ^ want;
          }
          if (__all(bad == 0)) break;
          __builtin_amdgcn_s_sleep(1);
        }
        uint4* d4 = (uint4*)dst;
#pragma unroll
        for (int i = 0; i < 4; ++i) {
          uint4 w4;
          w4.x = pay[4 * i + 0]; w4.y = pay[4 * i + 1];
          w4.z = pay[4 * i + 2]; w4.w = pay[4 * i + 3];
          d4[i] = w4;
        }
      }
    }
    __syncthreads();  // b2: hstage ready

    if (kg >= 2) {
      const int kh0 = (kg - 2) * 256 + q * 8;
#pragma unroll
      for (int kt = 0; kt < 8; ++kt) {
        const int kh = kh0 + kt * 32;
        short8 bA = *(const short8*)&hstage[(size_t)ln * LDSROW + kh];
        short8 bB = *(const short8*)&hstage[(size_t)(16 + ln) * LDSROW + kh];
        acc0 = __builtin_amdgcn_mfma_f32_16x16x32_bf16(afrag[kt], bA, acc0, 0, 0, 0);
        acc1 = __builtin_amdgcn_mfma_f32_16x16x32_bf16(afrag[kt], bB, acc1, 0, 0, 0);
      }
      const int sg = s * 4 + kg;
#pragma unroll
      for (int r = 0; r < 4; ++r) {
        partials[sg][q * 4 + r][ln] = acc0[r];
        partials[sg][q * 4 + r][16 + ln] = acc1[r];
      }
    }
    __syncthreads();  // b3: all partials ready

    if (tid < 256) {
      const int m0 = elp * 2, m1 = elp * 2 + 1;
      float gi0 = partials[0][m0][eb] + partials[1][m0][eb] + partials[2][m0][eb] + partials[3][m0][eb];
      float gi1 = partials[0][m1][eb] + partials[1][m1][eb] + partials[2][m1][eb] + partials[3][m1][eb];
      float gf0 = partials[4][m0][eb] + partials[5][m0][eb] + partials[6][m0][eb] + partials[7][m0][eb];
      float gf1 = partials[4][m1][eb] + partials[5][m1][eb] + partials[6][m1][eb] + partials[7][m1][eb];
      float go0 = partials[8][m0][eb] + partials[9][m0][eb] + partials[10][m0][eb] + partials[11][m0][eb];
      float go1 = partials[8][m1][eb] + partials[9][m1][eb] + partials[10][m1][eb] + partials[11][m1][eb];
      float gm0 = partials[12][m0][eb] + partials[13][m0][eb] + partials[14][m0][eb] + partials[15][m0][eb];
      float gm1 = partials[12][m1][eb] + partials[13][m1][eb] + partials[14][m1][eb] + partials[15][m1][eb];

      float i0 = sigm(gi0 + bi0), i1 = sigm(gi1 + bi1);
      float f0 = sigm(gf0 + bfg0), f1 = sigm(gf1 + bfg1);
      float o0 = sigm(go0 + bo0), o1 = sigm(go1 + bo1);
      float mm0 = tanh_f(gm0 + bm0), mm1 = tanh_f(gm1 + bm1);
      cc0 = f0 * cc0 + i0 * mm0;
      cc1 = f1 * cc1 + i1 * mm1;
      float hv0 = o0 * tanh_f(cc0);
      float hv1 = o1 * tanh_f(cc1);

      // publish h packet first (critical path), THEN the streaming outputs
      union { unsigned short us[2]; unsigned int u32; } pk;
      pk.us[0] = f2bf(hv0);
      pk.us[1] = f2bf(hv1);
      unsigned long long pkt =
          ((unsigned long long)(unsigned int)t << 32) | (unsigned long long)pk.u32;
      __hip_atomic_store(
          hbuf64 + (size_t)(t & 1) * PKTS + (size_t)eb * 256 + (ecol >> 1),
          pkt, __ATOMIC_RELAXED, __HIP_MEMORY_SCOPE_AGENT);

      const size_t obase = ((size_t)eb * TT + (t - 1)) * LL + ecol;
      float2 hh; hh.x = hv0; hh.y = hv1;
      float2 cv; cv.x = cc0; cv.y = cc1;
      *(float2*)(out + obase) = hh;
      *(float2*)(out + HSZ + obase) = cv;
    }
    __syncthreads();  // b4: partials/hstage consumed; loop
  }
}

extern "C" void kernel_launch(void* const* d_in, const int* in_sizes, int n_in,
                              void* d_out, int out_size, void* d_ws, size_t ws_size,
                              hipStream_t stream) {
  const float* x   = (const float*)d_in[0];
  const float* h0  = (const float*)d_in[1];
  const float* c0  = (const float*)d_in[2];
  const float* w_w = (const float*)d_in[3];
  const float* w_b = (const float*)d_in[4];
  const float* m_w = (const float*)d_in[5];
  const float* m_b = (const float*)d_in[6];
  float* out = (float*)d_out;

  // 2 phases x 8192 u64 packets = 128 KiB of workspace; tags make any
  // stale/poisoned contents unmatchable, so no memset is needed.
  unsigned long long* hbuf64 = (unsigned long long*)d_ws;

  hipLaunchKernelGGL(lstm_persistent, dim3(NBLK), dim3(1024), 0, stream,
                     x, h0, c0, w_w, w_b, m_w, m_b, out, hbuf64);
}

// Round 2
// 16146.301 us; speedup vs baseline: 1.8031x; 1.8031x over previous
//
#include <hip/hip_runtime.h>
#include <cstddef>

#define BB 32
#define TT 2048
#define DD 512
#define LL 512
#define NBLK 32
#define HSZ ((size_t)BB * TT * LL)
#define XROW 520     // bf16 elems per staged row (512 + 8 pad), hstage & xtile
#define PKTS 8192    // u64 packets per phase (32 * 512 / 2)

typedef __attribute__((ext_vector_type(8))) short short8;
typedef __attribute__((ext_vector_type(4))) float floatx4;

__device__ __forceinline__ unsigned short f2bf(float f) {
  __bf16 b = (__bf16)f;
  return __builtin_bit_cast(unsigned short, b);
}

__device__ __forceinline__ short8 pack2(const float4& a, const float4& b) {
  short8 r;
  r[0] = (short)f2bf(a.x); r[1] = (short)f2bf(a.y);
  r[2] = (short)f2bf(a.z); r[3] = (short)f2bf(a.w);
  r[4] = (short)f2bf(b.x); r[5] = (short)f2bf(b.y);
  r[6] = (short)f2bf(b.z); r[7] = (short)f2bf(b.w);
  return r;
}

__device__ __forceinline__ float sigm(float v) {
  return 1.0f / (1.0f + __expf(-v));
}
__device__ __forceinline__ float tanh_f(float v) {
  return 1.0f - 2.0f / (__expf(2.0f * v) + 1.0f);
}

// 32 persistent blocks; block j owns col-slice `slice` (XCD-paired swizzle).
// Cross-block h-exchange: single-hop tag-in-data u64 packets (tag<<32|bf16x2)
// via relaxed agent atomics. 2-phase ping-pong WAR-safe transitively.
//
// NEW this round: x is software-pipelined one step ahead through an LDS bf16
// tile (same 520-stride layout as hstage), so phase A's x-MFMA is pure
// LDS->MFMA (~400cyc) instead of ~8-10 serialized IC round-trips under the
// tiny VGPR budget. Prefetch loads for x(t+1) are issued at phase-C start
// (reg-staged, T14 split): they fly under the epilogue; pack+ds_write land
// before b4, whose implicit vmcnt/lgkmcnt drain publishes the tile for free.
__global__ __launch_bounds__(1024, 4) void lstm_persistent(
    const float* __restrict__ x, const float* __restrict__ h0p,
    const float* __restrict__ c0p, const float* __restrict__ w_w,
    const float* __restrict__ w_b, const float* __restrict__ m_w,
    const float* __restrict__ m_b, float* __restrict__ out,
    unsigned long long* __restrict__ hbuf64) {
  const int j = blockIdx.x;
  const int slice = ((j & 7) << 2) | (j >> 3);  // same-XCD blocks -> adjacent slices
  const int tid = threadIdx.x;
  const int wave = tid >> 6;
  const int lane = tid & 63;
  const int s = wave & 3;    // 0=i, 1=f, 2=o, 3=mem strip
  const int kg = wave >> 2;  // 0,1 = x half; 2,3 = h half
  const int q = lane >> 4;
  const int ln = lane & 15;

  __shared__ __align__(16) float partials[16][16][36];
  __shared__ __align__(16) unsigned short hstage[32 * XROW];
  __shared__ __align__(16) unsigned short xtile[32 * XROW];

  // ---- preload A fragments: W^T slice (k rows 0..1023 = [x|h]) ----
  short8 afrag[8];
  {
    const float* Wsrc;
    int wstride, col;
    if (s < 3) { Wsrc = w_w; wstride = 3 * LL; col = s * LL + slice * 16 + ln; }
    else       { Wsrc = m_w; wstride = LL;     col = slice * 16 + ln; }
#pragma unroll
    for (int kt = 0; kt < 8; ++kt) {
      const int kb = kg * 256 + kt * 32 + q * 8;
      short8 f;
#pragma unroll
      for (int jj = 0; jj < 8; ++jj)
        f[jj] = (short)f2bf(Wsrc[(size_t)(kb + jj) * wstride + col]);
      afrag[kt] = f;
    }
  }

  // ---- epilogue thread state: tid<256 -> (batch eb, l-pair elp) ----
  const int eb = tid >> 3;
  const int elp = tid & 7;
  const int ecol = slice * 16 + elp * 2;
  float cc0 = 0.f, cc1 = 0.f;
  float bi0 = 0, bi1 = 0, bfg0 = 0, bfg1 = 0, bo0 = 0, bo1 = 0, bm0 = 0, bm1 = 0;
  if (tid < 256) {
    cc0 = c0p[eb * LL + ecol];
    cc1 = c0p[eb * LL + ecol + 1];
    bi0 = w_b[ecol];            bi1 = w_b[ecol + 1];
    bfg0 = w_b[LL + ecol];      bfg1 = w_b[LL + ecol + 1];
    bo0 = w_b[2 * LL + ecol];   bo1 = w_b[2 * LL + ecol + 1];
    bm0 = m_b[ecol];            bm1 = m_b[ecol + 1];
  }

  // ---- x-prefetch lane mapping (x-waves, tid<512): batch xb, 16B seg xseg.
  // Load j: lanes read contiguous 256B (seg*16B within j*256B chunk).
  const int xb = tid >> 4;
  const int xseg = tid & 15;

  // ---- preload xtile with x column 0 ----
  if (kg < 2) {
    const float* src = x + (size_t)xb * TT * DD;  // t=0
    float4 xf[8];
#pragma unroll
    for (int jj = 0; jj < 8; ++jj)
      xf[jj] = *(const float4*)(src + jj * 64 + xseg * 4);
#pragma unroll
    for (int jj = 0; jj < 8; ++jj) {
      union { unsigned short us[4]; uint2 u2; } pk;
      pk.us[0] = f2bf(xf[jj].x); pk.us[1] = f2bf(xf[jj].y);
      pk.us[2] = f2bf(xf[jj].z); pk.us[3] = f2bf(xf[jj].w);
      *(uint2*)&xtile[xb * XROW + jj * 64 + xseg * 4] = pk.u2;
    }
  }
  __syncthreads();

#pragma unroll 1
  for (int t = 1; t <= TT; ++t) {
    floatx4 acc0 = {0.f, 0.f, 0.f, 0.f};
    floatx4 acc1 = {0.f, 0.f, 0.f, 0.f};

    if (kg < 2) {
      // ---- phase A: x contribution, pure LDS (tile staged last step) ----
      const int kx0 = kg * 256 + q * 8;
#pragma unroll
      for (int kt = 0; kt < 8; ++kt) {
        const int kx = kx0 + kt * 32;
        short8 bA = *(const short8*)&xtile[(size_t)ln * XROW + kx];
        short8 bB = *(const short8*)&xtile[(size_t)(16 + ln) * XROW + kx];
        acc0 = __builtin_amdgcn_mfma_f32_16x16x32_bf16(afrag[kt], bA, acc0, 0, 0, 0);
        acc1 = __builtin_amdgcn_mfma_f32_16x16x32_bf16(afrag[kt], bB, acc1, 0, 0, 0);
      }
      const int sg = s * 4 + kg;
#pragma unroll
      for (int r = 0; r < 4; ++r) {
        partials[sg][q * 4 + r][ln] = acc0[r];
        partials[sg][q * 4 + r][16 + ln] = acc1[r];
      }
    } else {
      // ---- stage h(t-1) into LDS: 512 threads x 64 B, poll tags in-data ----
      const int idx = tid - 512;
      const int b = idx & 31;
      const int g = idx >> 5;
      unsigned short* dst = &hstage[b * XROW + g * 32];
      if (t == 1) {
        const float* src = h0p + b * LL + g * 32;
#pragma unroll
        for (int i = 0; i < 4; ++i) {
          float4 a0 = *(const float4*)(src + i * 8);
          float4 a1 = *(const float4*)(src + i * 8 + 4);
          *(short8*)(dst + i * 8) = pack2(a0, a1);
        }
      } else {
        const unsigned long long* src =
            hbuf64 + (size_t)((t - 1) & 1) * PKTS + (size_t)b * 256 + g * 16;
        const unsigned int want = (unsigned int)(t - 1);
        unsigned int pay[16];
        for (;;) {
          unsigned int bad = 0;
#pragma unroll
          for (int p = 0; p < 16; ++p) {
            unsigned long long v = __hip_atomic_load(
                src + p, __ATOMIC_RELAXED, __HIP_MEMORY_SCOPE_AGENT);
            pay[p] = (unsigned int)v;
            bad |= ((unsigned int)(v >> 32)) ^ want;
          }
          if (__all(bad == 0)) break;
          __builtin_amdgcn_s_sleep(1);
        }
        uint4* d4 = (uint4*)dst;
#pragma unroll
        for (int i = 0; i < 4; ++i) {
          uint4 w4;
          w4.x = pay[4 * i + 0]; w4.y = pay[4 * i + 1];
          w4.z = pay[4 * i + 2]; w4.w = pay[4 * i + 3];
          d4[i] = w4;
        }
      }
    }
    __syncthreads();  // b2: hstage ready, xtile consumed

    if (kg >= 2) {
      const int kh0 = (kg - 2) * 256 + q * 8;
#pragma unroll
      for (int kt = 0; kt < 8; ++kt) {
        const int kh = kh0 + kt * 32;
        short8 bA = *(const short8*)&hstage[(size_t)ln * XROW + kh];
        short8 bB = *(const short8*)&hstage[(size_t)(16 + ln) * XROW + kh];
        acc0 = __builtin_amdgcn_mfma_f32_16x16x32_bf16(afrag[kt], bA, acc0, 0, 0, 0);
        acc1 = __builtin_amdgcn_mfma_f32_16x16x32_bf16(afrag[kt], bB, acc1, 0, 0, 0);
      }
      const int sg = s * 4 + kg;
#pragma unroll
      for (int r = 0; r < 4; ++r) {
        partials[sg][q * 4 + r][ln] = acc0[r];
        partials[sg][q * 4 + r][16 + ln] = acc1[r];
      }
    }
    __syncthreads();  // b3: all partials ready

    // ---- phase C: issue x(t+1) loads first (fly under epilogue) ----
    const bool doPre = (kg < 2) && (t < TT);
    float4 xf[8];
    if (doPre) {
      const float* src = x + ((size_t)xb * TT + t) * DD;
#pragma unroll
      for (int jj = 0; jj < 8; ++jj)
        xf[jj] = *(const float4*)(src + jj * 64 + xseg * 4);
    }

    if (tid < 256) {
      const int m0 = elp * 2, m1 = elp * 2 + 1;
      float gi0 = partials[0][m0][eb] + partials[1][m0][eb] + partials[2][m0][eb] + partials[3][m0][eb];
      float gi1 = partials[0][m1][eb] + partials[1][m1][eb] + partials[2][m1][eb] + partials[3][m1][eb];
      float gf0 = partials[4][m0][eb] + partials[5][m0][eb] + partials[6][m0][eb] + partials[7][m0][eb];
      float gf1 = partials[4][m1][eb] + partials[5][m1][eb] + partials[6][m1][eb] + partials[7][m1][eb];
      float go0 = partials[8][m0][eb] + partials[9][m0][eb] + partials[10][m0][eb] + partials[11][m0][eb];
      float go1 = partials[8][m1][eb] + partials[9][m1][eb] + partials[10][m1][eb] + partials[11][m1][eb];
      float gm0 = partials[12][m0][eb] + partials[13][m0][eb] + partials[14][m0][eb] + partials[15][m0][eb];
      float gm1 = partials[12][m1][eb] + partials[13][m1][eb] + partials[14][m1][eb] + partials[15][m1][eb];

      float i0 = sigm(gi0 + bi0), i1 = sigm(gi1 + bi1);
      float f0 = sigm(gf0 + bfg0), f1 = sigm(gf1 + bfg1);
      float o0 = sigm(go0 + bo0), o1 = sigm(go1 + bo1);
      float mm0 = tanh_f(gm0 + bm0), mm1 = tanh_f(gm1 + bm1);
      cc0 = f0 * cc0 + i0 * mm0;
      cc1 = f1 * cc1 + i1 * mm1;
      float hv0 = o0 * tanh_f(cc0);
      float hv1 = o1 * tanh_f(cc1);

      // publish h packet first (critical path), THEN the streaming outputs
      union { unsigned short us[2]; unsigned int u32; } pk;
      pk.us[0] = f2bf(hv0);
      pk.us[1] = f2bf(hv1);
      unsigned long long pkt =
          ((unsigned long long)(unsigned int)t << 32) | (unsigned long long)pk.u32;
      __hip_atomic_store(
          hbuf64 + (size_t)(t & 1) * PKTS + (size_t)eb * 256 + (ecol >> 1),
          pkt, __ATOMIC_RELAXED, __HIP_MEMORY_SCOPE_AGENT);

      const size_t obase = ((size_t)eb * TT + (t - 1)) * LL + ecol;
      float2 hh; hh.x = hv0; hh.y = hv1;
      float2 cv; cv.x = cc0; cv.y = cc1;
      *(float2*)(out + obase) = hh;
      *(float2*)(out + HSZ + obase) = cv;
    }

    if (doPre) {
      // pack x(t+1) to bf16 and commit to xtile; b4's implicit lgkmcnt drain
      // makes it visible to next step's phase A.
#pragma unroll
      for (int jj = 0; jj < 8; ++jj) {
        union { unsigned short us[4]; uint2 u2; } pk;
        pk.us[0] = f2bf(xf[jj].x); pk.us[1] = f2bf(xf[jj].y);
        pk.us[2] = f2bf(xf[jj].z); pk.us[3] = f2bf(xf[jj].w);
        *(uint2*)&xtile[xb * XROW + jj * 64 + xseg * 4] = pk.u2;
      }
    }
    __syncthreads();  // b4: partials/hstage/xtile consumed & restaged; loop
  }
}

extern "C" void kernel_launch(void* const* d_in, const int* in_sizes, int n_in,
                              void* d_out, int out_size, void* d_ws, size_t ws_size,
                              hipStream_t stream) {
  const float* x   = (const float*)d_in[0];
  const float* h0  = (const float*)d_in[1];
  const float* c0  = (const float*)d_in[2];
  const float* w_w = (const float*)d_in[3];
  const float* w_b = (const float*)d_in[4];
  const float* m_w = (const float*)d_in[5];
  const float* m_b = (const float*)d_in[6];
  float* out = (float*)d_out;

  // 2 phases x 8192 u64 packets = 128 KiB of workspace; tags make any
  // stale/poisoned contents unmatchable, so no memset is needed.
  unsigned long long* hbuf64 = (unsigned long long*)d_ws;

  hipLaunchKernelGGL(lstm_persistent, dim3(NBLK), dim3(1024), 0, stream,
                     x, h0, c0, w_w, w_b, m_w, m_b, out, hbuf64);
}